// Round 1
// baseline (69185.529 us; speedup 1.0000x reference)
//
#include <hip/hip_runtime.h>

// HighwayLayerDiscrete: 256-step recurrent highway net, batch 64, units 1024.
// Phase P = t*4+p: p0: h=lrelu(y@w_y + xproj[t]); p1/p2: h=lrelu(h@w_h[l]+b_h[l]);
// p3: y += h@w_out + b_out, write out[:,t,:].
// Design: xproj precomputed (parallel GEMM). Sequential part: 256 WGs =
// 16 col-groups(c) x 16 K-groups(s), flag-based producer/consumer pipeline
// (no global barriers). Split-K partials (K-slice 64) + per-col-group reduce.

constexpr int B = 64, T = 256, U = 1024, E = 512;
constexpr int BU = B * U;  // 65536

#define LRELU(v) ((v) > 0.f ? (v) : 0.2f * (v))

// ---------------- init: zero flags, broadcast h0 into y ----------------
__global__ void k_init(float* __restrict__ y, const float* __restrict__ h0,
                       unsigned* __restrict__ flags) {
  int tid = blockIdx.x * 256 + threadIdx.x;
  if (tid < 1024) flags[tid] = 0u;
  if (tid < BU) y[tid] = h0[tid & (U - 1)];
}

// ---------------- xproj[t*64+n][u] = emb[x[n][t]] @ w_x + b_in ----------------
// M=16384 (row = t*64+n), N=1024, K=512. Tile 64x64, thread 4x4, K-chunk 32.
__global__ __launch_bounds__(256) void k_xproj(
    const int* __restrict__ x, const float* __restrict__ emb,
    const float* __restrict__ w_x, const float* __restrict__ b_in,
    float* __restrict__ xp) {
  __shared__ float a_t[32][68];  // [k][row], stride 68 keeps float4 alignment
  __shared__ float w_s[32][64];
  __shared__ int idxs[64];
  const int tid = threadIdx.x;
  const int m0 = blockIdx.x * 64;
  const int c0 = blockIdx.y * 64;
  if (tid < 64) {
    int m = m0 + tid;
    idxs[tid] = x[(m & 63) * T + (m >> 6)];  // x[n][t], row m = t*64+n
  }
  __syncthreads();
  const int rq = tid >> 4, cq = tid & 15;
  float acc[4][4] = {};
  for (int k0 = 0; k0 < E; k0 += 32) {
#pragma unroll
    for (int rep = 0; rep < 2; ++rep) {  // A: 64 rows x 8 float4
      int e = rep * 256 + tid;
      int r = e >> 3, q = e & 7;
      float4 v = *(const float4*)(emb + (size_t)idxs[r] * E + k0 + 4 * q);
      a_t[4 * q + 0][r] = v.x;
      a_t[4 * q + 1][r] = v.y;
      a_t[4 * q + 2][r] = v.z;
      a_t[4 * q + 3][r] = v.w;
    }
#pragma unroll
    for (int rep = 0; rep < 2; ++rep) {  // W: 32 k x 16 float4
      int e = rep * 256 + tid;
      int kr = e >> 4, q = e & 15;
      *(float4*)&w_s[kr][4 * q] =
          *(const float4*)(w_x + (size_t)(k0 + kr) * U + c0 + 4 * q);
    }
    __syncthreads();
#pragma unroll 8
    for (int k = 0; k < 32; ++k) {
      float4 a4 = *(const float4*)&a_t[k][4 * rq];
      float4 w4 = *(const float4*)&w_s[k][4 * cq];
      float av[4] = {a4.x, a4.y, a4.z, a4.w};
      float wv[4] = {w4.x, w4.y, w4.z, w4.w};
#pragma unroll
      for (int i = 0; i < 4; ++i)
#pragma unroll
        for (int j = 0; j < 4; ++j) acc[i][j] += av[i] * wv[j];
    }
    __syncthreads();
  }
  const float4 bb = *(const float4*)(b_in + c0 + 4 * cq);
  float bv[4] = {bb.x, bb.y, bb.z, bb.w};
#pragma unroll
  for (int i = 0; i < 4; ++i) {
    float4 o;
    o.x = acc[i][0] + bv[0];
    o.y = acc[i][1] + bv[1];
    o.z = acc[i][2] + bv[2];
    o.w = acc[i][3] + bv[3];
    *(float4*)(xp + (size_t)(m0 + 4 * rq + i) * U + c0 + 4 * cq) = o;
  }
}

// ---------------- sequential pipeline ----------------
// WG (c,s): produce partial[cols 64c..][k in 64s..64s+64), then reduce
// rows 4s..4s+4 of col-group c. Flags are cumulative arrival counters
// (16 per phase), padded to 128B lines. hflag[g] counts reduce-completions
// of col-group g; pflag[g] counts partial-completions for col-group g.
__global__ __launch_bounds__(256, 1) void k_seq(
    const float* __restrict__ xproj, const float* __restrict__ w_y,
    const float* __restrict__ w_h, const float* __restrict__ b_h,
    const float* __restrict__ w_out, const float* __restrict__ b_out,
    float* __restrict__ out, float* __restrict__ y, float* __restrict__ hbuf,
    float* __restrict__ part, unsigned* __restrict__ pflag,
    unsigned* __restrict__ hflag) {
  __shared__ float a_t[64][68];  // [k_local][row]
  __shared__ float w_s[64][64];  // [k_local][col_local]
  const int tid = threadIdx.x;
  const int c = blockIdx.x & 15;   // col-group
  const int s = blockIdx.x >> 4;   // K-group
  const int rq = tid >> 4, cq = tid & 15;

  for (int P = 0; P < 4 * T; ++P) {
    const int t = P >> 2, p = P & 3;
    const float* Asrc = (p == 0) ? y : hbuf + (size_t)((P - 1) & 1) * BU;
    const float* Wsrc = (p == 0)   ? w_y
                        : (p == 3) ? w_out
                                   : w_h + (size_t)(p - 1) * U * U;
    // ---- wait for A k-slice (cols 64s..64s+64 of previous phase) ----
    if (P > 0) {
      if (tid == 0) {
        const unsigned target = 16u * (unsigned)P;
        while (__hip_atomic_load(&hflag[s * 32], __ATOMIC_RELAXED,
                                 __HIP_MEMORY_SCOPE_AGENT) < target)
          __builtin_amdgcn_s_sleep(1);
      }
      __syncthreads();
      (void)__hip_atomic_load(&hflag[s * 32], __ATOMIC_ACQUIRE,
                              __HIP_MEMORY_SCOPE_AGENT);
    }
    // ---- stage A (transposed) and W ----
#pragma unroll
    for (int rep = 0; rep < 4; ++rep) {  // 64 rows x 16 float4
      int e = rep * 256 + tid;
      int r = e >> 4, q = e & 15;
      float4 v = *(const float4*)(Asrc + (size_t)r * U + s * 64 + 4 * q);
      a_t[4 * q + 0][r] = v.x;
      a_t[4 * q + 1][r] = v.y;
      a_t[4 * q + 2][r] = v.z;
      a_t[4 * q + 3][r] = v.w;
    }
#pragma unroll
    for (int rep = 0; rep < 4; ++rep) {  // 64 k x 16 float4
      int e = rep * 256 + tid;
      int kr = e >> 4, q = e & 15;
      *(float4*)&w_s[kr][4 * q] =
          *(const float4*)(Wsrc + (size_t)(s * 64 + kr) * U + c * 64 + 4 * q);
    }
    __syncthreads();
    // ---- compute 64x64 partial over K-slice of 64 ----
    float acc[4][4] = {};
#pragma unroll 16
    for (int k = 0; k < 64; ++k) {
      float4 a4 = *(const float4*)&a_t[k][4 * rq];
      float4 w4 = *(const float4*)&w_s[k][4 * cq];
      float av[4] = {a4.x, a4.y, a4.z, a4.w};
      float wv[4] = {w4.x, w4.y, w4.z, w4.w};
#pragma unroll
      for (int i = 0; i < 4; ++i)
#pragma unroll
        for (int j = 0; j < 4; ++j) acc[i][j] += av[i] * wv[j];
    }
    float* pdst = part + ((size_t)(P & 1) * 16 + s) * BU;
#pragma unroll
    for (int i = 0; i < 4; ++i) {
      float4 o;
      o.x = acc[i][0];
      o.y = acc[i][1];
      o.z = acc[i][2];
      o.w = acc[i][3];
      *(float4*)(pdst + (size_t)(4 * rq + i) * U + c * 64 + 4 * cq) = o;
    }
    __threadfence();  // release partial data (agent scope)
    __syncthreads();
    if (tid == 0)
      __hip_atomic_fetch_add(&pflag[c * 32], 1u, __ATOMIC_RELEASE,
                             __HIP_MEMORY_SCOPE_AGENT);
    // ---- reduce: rows 4s..4s+4 of col-group c ----
    if (tid == 0) {
      const unsigned target = 16u * (unsigned)(P + 1);
      while (__hip_atomic_load(&pflag[c * 32], __ATOMIC_RELAXED,
                               __HIP_MEMORY_SCOPE_AGENT) < target)
        __builtin_amdgcn_s_sleep(1);
    }
    __syncthreads();
    (void)__hip_atomic_load(&pflag[c * 32], __ATOMIC_ACQUIRE,
                            __HIP_MEMORY_SCOPE_AGENT);
    {
      const int r = 4 * s + (tid >> 6);
      const int u = c * 64 + (tid & 63);
      const float* psrc = part + (size_t)(P & 1) * 16 * BU;
      float sum = 0.f;
#pragma unroll
      for (int s2 = 0; s2 < 16; ++s2)
        sum += psrc[(size_t)s2 * BU + r * U + u];
      if (p == 0) {
        float v = sum + xproj[((size_t)t * B + r) * U + u];
        v = LRELU(v);
        hbuf[(size_t)(P & 1) * BU + r * U + u] = v;
      } else if (p < 3) {
        float v = sum + b_h[(p - 1) * U + u];
        v = LRELU(v);
        hbuf[(size_t)(P & 1) * BU + r * U + u] = v;
      } else {
        float yn = y[r * U + u] + sum + b_out[u];
        y[r * U + u] = yn;
        out[((size_t)r * T + t) * U + u] = yn;
      }
    }
    __threadfence();  // release h / y
    __syncthreads();
    if (tid == 0)
      __hip_atomic_fetch_add(&hflag[c * 32], 1u, __ATOMIC_RELEASE,
                             __HIP_MEMORY_SCOPE_AGENT);
  }
}

extern "C" void kernel_launch(void* const* d_in, const int* in_sizes, int n_in,
                              void* d_out, int out_size, void* d_ws,
                              size_t ws_size, hipStream_t stream) {
  const int* x = (const int*)d_in[0];
  const float* emb = (const float*)d_in[1];
  const float* w_y = (const float*)d_in[2];
  const float* w_x = (const float*)d_in[3];
  const float* b_in = (const float*)d_in[4];
  const float* w_h = (const float*)d_in[5];
  const float* b_h = (const float*)d_in[6];
  const float* w_out = (const float*)d_in[7];
  const float* b_out = (const float*)d_in[8];
  const float* h0 = (const float*)d_in[9];
  float* out = (float*)d_out;

  // workspace layout (floats): xproj | y | hbuf[2] | part[2][16] | flags
  float* ws = (float*)d_ws;
  float* xp = ws;                           // T*B*U = 16777216
  float* y = xp + (size_t)T * B * U;        // BU
  float* hbuf = y + BU;                     // 2*BU
  float* part = hbuf + 2 * (size_t)BU;      // 32*BU
  unsigned* flags = (unsigned*)(part + 32 * (size_t)BU);  // 1024 uints
  unsigned* pflag = flags;
  unsigned* hflag = flags + 512;

  k_init<<<256, 256, 0, stream>>>(y, h0, flags);
  dim3 g1(256, 16);
  k_xproj<<<g1, 256, 0, stream>>>(x, emb, w_x, b_in, xp);

  void* args[] = {&xp, &w_y, &w_h, &b_h, &w_out, &b_out,
                  &out, &y,  &hbuf, &part, &pflag, &hflag};
  hipLaunchCooperativeKernel((void*)k_seq, dim3(256), dim3(256), args, 0u,
                             stream);
}

// Round 2
// 15544.885 us; speedup vs baseline: 4.4507x; 4.4507x over previous
//
#include <hip/hip_runtime.h>

// HighwayLayerDiscrete: 256-step recurrent highway net, batch 64, units 1024.
// Phase P = t*4+p: p0: h=lrelu(y@w_y + xproj[t]); p1/p2: h=lrelu(h@w_h[l]+b_h[l]);
// p3: y += h@w_out + b_out, write out[:,t,:].
//
// R2 design change vs R1: NO FENCES. R1 used __threadfence/acquire (agent
// scope) which lowers to buffer_wbl2/buffer_inv — full per-XCD L2
// writeback/invalidate per phase per WG -> 66 ms (VALUBusy 1.7%). Now all
// cross-WG data (y, hbuf, partials) moves via relaxed agent-scope atomics
// (global_load/store sc1, serviced at the LLC = device coherence point).
// Release = s_waitcnt vmcnt(0) + barrier + relaxed flag add. Acquire = in-order
// vmem issue + asm memory clobber. Weights are plain loads -> stay hot in
// L1/L2 (never invalidated).

constexpr int B = 64, T = 256, U = 1024, E = 512;
constexpr int BU = B * U;  // 65536

#define LRELU(v) ((v) > 0.f ? (v) : 0.2f * (v))

__device__ __forceinline__ float llc_load(const float* p) {
  return __hip_atomic_load(p, __ATOMIC_RELAXED, __HIP_MEMORY_SCOPE_AGENT);
}
__device__ __forceinline__ void llc_store(float* p, float v) {
  __hip_atomic_store(p, v, __ATOMIC_RELAXED, __HIP_MEMORY_SCOPE_AGENT);
}
// Whole-wave poll (same address across lanes -> 1 coalesced LLC request).
__device__ __forceinline__ void wait_flag(const unsigned* f, unsigned target) {
  while (__hip_atomic_load(f, __ATOMIC_RELAXED, __HIP_MEMORY_SCOPE_AGENT) <
         target) {
  }
  asm volatile("" ::: "memory");  // block compiler hoisting data loads above
}

// ---------------- init: zero flags, broadcast h0 into y ----------------
__global__ void k_init(float* __restrict__ y, const float* __restrict__ h0,
                       unsigned* __restrict__ flags) {
  int tid = blockIdx.x * 256 + threadIdx.x;
  if (tid < 1024) flags[tid] = 0u;
  if (tid < BU) y[tid] = h0[tid & (U - 1)];
}

// ---------------- xproj[t*64+n][u] = emb[x[n][t]] @ w_x + b_in ----------------
// M=16384 (row m = t*64+n), N=1024, K=512. Tile 64x64, thread 4x4, K-chunk 32.
// A staged un-transposed a_s[r][k] (stride 36 -> banks 4r+k, conflict-free);
// compute reads are k-chunk-4 float4 broadcasts.
__global__ __launch_bounds__(256) void k_xproj(
    const int* __restrict__ x, const float* __restrict__ emb,
    const float* __restrict__ w_x, const float* __restrict__ b_in,
    float* __restrict__ xp) {
  __shared__ float a_s[64][36];
  __shared__ float w_s[32][64];
  __shared__ int idxs[64];
  const int tid = threadIdx.x;
  const int m0 = blockIdx.x * 64;
  const int c0 = blockIdx.y * 64;
  if (tid < 64) {
    int m = m0 + tid;
    idxs[tid] = x[(m & 63) * T + (m >> 6)];  // x[n][t], row m = t*64+n
  }
  __syncthreads();
  const int rq = tid >> 4, cq = tid & 15;
  float acc[4][4] = {};
  for (int k0 = 0; k0 < E; k0 += 32) {
#pragma unroll
    for (int rep = 0; rep < 8; ++rep) {  // A: 64 rows x 32 k, scalar dwords
      int e = rep * 256 + tid;
      int r = e >> 5, k = e & 31;
      a_s[r][k] = emb[(size_t)idxs[r] * E + k0 + k];
    }
#pragma unroll
    for (int rep = 0; rep < 2; ++rep) {  // W: 32 k x 16 float4
      int e = rep * 256 + tid;
      int kr = e >> 4, q = e & 15;
      *(float4*)&w_s[kr][4 * q] =
          *(const float4*)(w_x + (size_t)(k0 + kr) * U + c0 + 4 * q);
    }
    __syncthreads();
#pragma unroll
    for (int kc = 0; kc < 32; kc += 4) {
      float4 a4[4], w4[4];
#pragma unroll
      for (int i = 0; i < 4; ++i) a4[i] = *(const float4*)&a_s[4 * rq + i][kc];
#pragma unroll
      for (int kk = 0; kk < 4; ++kk)
        w4[kk] = *(const float4*)&w_s[kc + kk][4 * cq];
#pragma unroll
      for (int i = 0; i < 4; ++i) {
        const float av[4] = {a4[i].x, a4[i].y, a4[i].z, a4[i].w};
#pragma unroll
        for (int kk = 0; kk < 4; ++kk) {
          acc[i][0] += av[kk] * w4[kk].x;
          acc[i][1] += av[kk] * w4[kk].y;
          acc[i][2] += av[kk] * w4[kk].z;
          acc[i][3] += av[kk] * w4[kk].w;
        }
      }
    }
    __syncthreads();
  }
  const float4 bb = *(const float4*)(b_in + c0 + 4 * cq);
  const float bv[4] = {bb.x, bb.y, bb.z, bb.w};
#pragma unroll
  for (int i = 0; i < 4; ++i) {
    float4 o;
    o.x = acc[i][0] + bv[0];
    o.y = acc[i][1] + bv[1];
    o.z = acc[i][2] + bv[2];
    o.w = acc[i][3] + bv[3];
    *(float4*)(xp + (size_t)(m0 + 4 * rq + i) * U + c0 + 4 * cq) = o;
  }
}

// ---------------- sequential pipeline ----------------
// 256 WGs = 16 col-groups(c) x 16 K-groups(s). Per phase: WG(c,s) produces
// partial (rows 0..63, cols 64c..64c+64, K-slice 64s..64s+64), posts pflag[c];
// then reduces rows 4s..4s+4 of col-group c over 16 partials, posts hflag[c].
// Flags: cumulative counters, 128B-padded. Depth-2 ping-pong on hbuf/part is
// ordered transitively through the flag chain (verified R1, structure kept).
__global__ __launch_bounds__(256, 1) void k_seq(
    const float* __restrict__ xproj, const float* __restrict__ w_y,
    const float* __restrict__ w_h, const float* __restrict__ b_h,
    const float* __restrict__ w_out, const float* __restrict__ b_out,
    float* __restrict__ out, float* __restrict__ y, float* __restrict__ hbuf,
    float* __restrict__ part, unsigned* __restrict__ pflag,
    unsigned* __restrict__ hflag) {
  __shared__ float a_s[64][68];  // [row][k_local], stride 68: banks 4r+k -> <=2-way
  __shared__ float w_s[64][64];  // [k_local][col_local]
  const int tid = threadIdx.x;
  const int c = blockIdx.x & 15;  // col-group
  const int s = blockIdx.x >> 4;  // K-group
  const int rq = tid >> 4, cq = tid & 15;

  for (int P = 0; P < 4 * T; ++P) {
    const int t = P >> 2, p = P & 3;
    const float* Asrc = (p == 0) ? y : hbuf + (size_t)((P - 1) & 1) * BU;
    const float* Wsrc = (p == 0)   ? w_y
                        : (p == 3) ? w_out
                                   : w_h + (size_t)(p - 1) * U * U;
    // ---- per-wave wait for A k-slice (cols 64s..64s+64 of prev phase) ----
    if (P > 0) wait_flag(&hflag[s * 32], 16u * (unsigned)P);
    // ---- stage A (LLC loads, scalar dwords, un-transposed) ----
#pragma unroll
    for (int rep = 0; rep < 16; ++rep) {  // 64 rows x 64 k
      int e = rep * 256 + tid;
      int r = e >> 6, k = e & 63;
      a_s[r][k] = llc_load(Asrc + (size_t)r * U + s * 64 + k);
    }
    // ---- stage W (plain cached loads — stays hot in L1/L2) ----
#pragma unroll
    for (int rep = 0; rep < 4; ++rep) {  // 64 k x 16 float4
      int e = rep * 256 + tid;
      int kr = e >> 4, q = e & 15;
      *(float4*)&w_s[kr][4 * q] =
          *(const float4*)(Wsrc + (size_t)(s * 64 + kr) * U + c * 64 + 4 * q);
    }
    __syncthreads();
    // ---- compute 64x64 partial over K-slice of 64 (k-chunks of 4) ----
    float acc[4][4] = {};
#pragma unroll
    for (int kc = 0; kc < 64; kc += 4) {
      float4 a4[4], w4[4];
#pragma unroll
      for (int i = 0; i < 4; ++i) a4[i] = *(const float4*)&a_s[4 * rq + i][kc];
#pragma unroll
      for (int kk = 0; kk < 4; ++kk)
        w4[kk] = *(const float4*)&w_s[kc + kk][4 * cq];
#pragma unroll
      for (int i = 0; i < 4; ++i) {
        const float av[4] = {a4[i].x, a4[i].y, a4[i].z, a4[i].w};
#pragma unroll
        for (int kk = 0; kk < 4; ++kk) {
          acc[i][0] += av[kk] * w4[kk].x;
          acc[i][1] += av[kk] * w4[kk].y;
          acc[i][2] += av[kk] * w4[kk].z;
          acc[i][3] += av[kk] * w4[kk].w;
        }
      }
    }
    // ---- store partial to LLC; release = vmcnt(0) + barrier + flag add ----
    {
      float* pdst = part + ((size_t)(P & 1) * 16 + s) * BU + c * 64 + 4 * cq;
#pragma unroll
      for (int i = 0; i < 4; ++i)
#pragma unroll
        for (int j = 0; j < 4; ++j)
          llc_store(pdst + (size_t)(4 * rq + i) * U + j, acc[i][j]);
    }
    asm volatile("" ::: "memory");
    __builtin_amdgcn_s_waitcnt(0);  // own wave's stores reached LLC
    __syncthreads();                // all waves' stores reached LLC
    if (tid == 0)
      __hip_atomic_fetch_add(&pflag[c * 32], 1u, __ATOMIC_RELAXED,
                             __HIP_MEMORY_SCOPE_AGENT);
    // ---- per-wave wait for all 16 partials of col-group c ----
    wait_flag(&pflag[c * 32], 16u * (unsigned)(P + 1));
    // ---- reduce rows 4s..4s+4 of col-group c (1 elem/thread) ----
    {
      const int r = 4 * s + (tid >> 6);
      const int u = c * 64 + (tid & 63);
      const float* psrc = part + (size_t)(P & 1) * 16 * BU + (size_t)r * U + u;
      float sum = 0.f;
#pragma unroll
      for (int s2 = 0; s2 < 16; ++s2) sum += llc_load(psrc + (size_t)s2 * BU);
      if (p == 0) {
        float v = LRELU(sum + xproj[((size_t)t * B + r) * U + u]);
        llc_store(hbuf + (size_t)(P & 1) * BU + r * U + u, v);
      } else if (p < 3) {
        float v = LRELU(sum + b_h[(p - 1) * U + u]);
        llc_store(hbuf + (size_t)(P & 1) * BU + r * U + u, v);
      } else {
        float yn = llc_load(y + (size_t)r * U + u) + sum + b_out[u];
        llc_store(y + (size_t)r * U + u, yn);
        out[((size_t)r * T + t) * U + u] = yn;  // plain store, never re-read
      }
    }
    asm volatile("" ::: "memory");
    __builtin_amdgcn_s_waitcnt(0);
    __syncthreads();
    if (tid == 0)
      __hip_atomic_fetch_add(&hflag[c * 32], 1u, __ATOMIC_RELAXED,
                             __HIP_MEMORY_SCOPE_AGENT);
  }
}

extern "C" void kernel_launch(void* const* d_in, const int* in_sizes, int n_in,
                              void* d_out, int out_size, void* d_ws,
                              size_t ws_size, hipStream_t stream) {
  const int* x = (const int*)d_in[0];
  const float* emb = (const float*)d_in[1];
  const float* w_y = (const float*)d_in[2];
  const float* w_x = (const float*)d_in[3];
  const float* b_in = (const float*)d_in[4];
  const float* w_h = (const float*)d_in[5];
  const float* b_h = (const float*)d_in[6];
  const float* w_out = (const float*)d_in[7];
  const float* b_out = (const float*)d_in[8];
  const float* h0 = (const float*)d_in[9];
  float* out = (float*)d_out;

  // workspace layout (floats): xproj | y | hbuf[2] | part[2][16] | flags
  float* ws = (float*)d_ws;
  float* xp = ws;                       // T*B*U = 16777216
  float* y = xp + (size_t)T * B * U;    // BU
  float* hbuf = y + BU;                 // 2*BU
  float* part = hbuf + 2 * (size_t)BU;  // 32*BU
  unsigned* flags = (unsigned*)(part + 32 * (size_t)BU);  // 1024 uints
  unsigned* pflag = flags;
  unsigned* hflag = flags + 512;

  k_init<<<256, 256, 0, stream>>>(y, h0, flags);
  dim3 g1(256, 16);
  k_xproj<<<g1, 256, 0, stream>>>(x, emb, w_x, b_in, xp);

  void* args[] = {&xp, &w_y, &w_h, &b_h, &w_out, &b_out,
                  &out, &y,  &hbuf, &part, &pflag, &hflag};
  hipLaunchCooperativeKernel((void*)k_seq, dim3(256), dim3(256), args, 0u,
                             stream);
}